// Round 19
// baseline (748.516 us; speedup 1.0000x reference)
//
#include <hip/hip_runtime.h>
#include <hip/hip_fp16.h>

// NoPropCTMomentNet: 10-step Euler of a 17->64->64->32->8 swish MLP, B=2M rows.
// Round 19 = R18 with HAZARD-SAFE inline-asm MFMA.
// R18's garbage output: raw asm MFMA bypasses LLVM's hazard recognizer; the
// multi-pass XDL write of D has no scoreboard interlock vs VALU readers.
// Fix: pad inside the asm block — s_nop 1 before (VALU-write -> MFMA-read),
// s_nop 7 x2 after (MFMA D-write -> VALU read, 16 cycles >= worst case).
// s_nop stalls only this wave; co-resident waves fill the slots.
// Goal unchanged: VGPR-form accumulators, no v_accvgpr marshal.

typedef __attribute__((ext_vector_type(8))) _Float16 half8;
typedef __attribute__((ext_vector_type(4))) float f32x4;

constexpr int NSTEP = 10;
constexpr float DT = 0.1f;
constexpr float LOG2E = 1.44269504f;
constexpr float LN2   = 0.69314718f;

__device__ __forceinline__ f32x4 mfma16(half8 a, half8 b, f32x4 c) {
    f32x4 d;
    asm volatile("s_nop 1\n\t"
                 "v_mfma_f32_16x16x32_f16 %0, %1, %2, %3\n\t"
                 "s_nop 7\n\t"
                 "s_nop 7"
                 : "=&v"(d) : "v"(a), "v"(b), "v"(c));
    return d;
}

__device__ __forceinline__ unsigned packh(float a, float b) {
    __half2 h = __floats2half2_rn(a, b);
    unsigned r; __builtin_memcpy(&r, &h, 4); return r;
}
__device__ __forceinline__ unsigned pkrtz(float a, float b) {
    auto z = __builtin_amdgcn_cvt_pkrtz(a, b);
    unsigned r; __builtin_memcpy(&r, &z, 4); return r;
}
__device__ __forceinline__ half8 mk8h(unsigned w0, unsigned w1,
                                      unsigned w2, unsigned w3) {
    union { unsigned w[4]; half8 h; } u;
    u.w[0] = w0; u.w[1] = w1; u.w[2] = w2; u.w[3] = w3;
    return u.h;
}

__device__ __forceinline__ void plswap16(unsigned& a, unsigned& b) {
    auto r = __builtin_amdgcn_permlane16_swap(a, b, false, false);
    a = r[0]; b = r[1];
}
__device__ __forceinline__ unsigned partner16(unsigned x) {
    unsigned a = x, b = x;
    plswap16(a, b);
    return b;
}

__device__ __forceinline__ __half2 bith2(unsigned u) {
    __half2 h; __builtin_memcpy(&h, &u, 4); return h;
}
__device__ __forceinline__ unsigned h2bit(__half2 h) {
    unsigned u; __builtin_memcpy(&u, &h, 4); return u;
}

// swish in scaled domain, 2 activations -> packed half2 word. Zero trans ops.
// g = max(z,0) + |z|*e*r(e);  e = 2^-|z| via f16 bit-trick
// bits = sat_u32(15324 - 1024|z|);  r(e) = -1/(1+e) deg-2 poly.
__device__ __forceinline__ unsigned swish2(float za, float zb) {
    const float ta = fmaf(__builtin_fabsf(za), -1024.0f, 15324.0f);
    const float tb = fmaf(__builtin_fabsf(zb), -1024.0f, 15324.0f);
    unsigned ua, ub;
    asm("v_cvt_u32_f32 %0, %1" : "=v"(ua) : "v"(ta));   // saturates: neg -> 0
    asm("v_cvt_u32_f32 %0, %1" : "=v"(ub) : "v"(tb));
    const unsigned eu = ua | (ub << 16);                // packed f16 pair e
    const unsigned zu = pkrtz(za, zb);
    __half2 z = bith2(zu), e = bith2(eu);
    __half2 az = __habs2(z);
    unsigned relu_u, zero_u = 0;
    asm("v_pk_max_f16 %0, %1, %2" : "=v"(relu_u) : "v"(zu), "v"(zero_u));
    const __half2 C0 = __float2half2_rn(-0.9903978f);
    const __half2 C1 = __float2half2_rn( 0.8141289f);
    const __half2 C2 = __float2half2_rn(-0.3292181f);
    __half2 s = __hmul2(az, e);
    __half2 r = __hfma2(e, __hfma2(e, C2, C1), C0);
    __half2 hh = __hfma2(s, r, bith2(relu_u));
    return h2bit(hh);
}

// A-fragment of W^T (chunk c, k-split s), fp16, scaled.
// PERM=true: k = 16(2s + (p>>1)) + 4hi + 2(p&1)  — matches prev-layer D layout.
template <int NOUT, int KLIM, bool M8, bool PERM>
__device__ __forceinline__ half8 wfragh(const float* __restrict__ W, float scale,
                                        int c, int s, int n, int hi) {
    unsigned w[4];
#pragma unroll
    for (int p = 0; p < 4; ++p) {
        const int k0 = PERM ? (16 * (2 * s + (p >> 1)) + 4 * hi + 2 * (p & 1))
                            : (32 * s + 8 * hi + 2 * p);
        const bool mok = !M8 || (n < 8);
        float a = (mok && (k0     < KLIM)) ? W[(size_t)k0 * NOUT + 16 * c + n] * scale : 0.0f;
        float b = (mok && (k0 + 1 < KLIM)) ? W[(size_t)(k0 + 1) * NOUT + 16 * c + n] * scale : 0.0f;
        w[p] = packh(a, b);
    }
    return mk8h(w[0], w[1], w[2], w[3]);
}

// W1 fragment with t-coeff at k=16 and bias at k=17 (virtual rows), scaled.
__device__ __forceinline__ half8 w1fragh(const float* __restrict__ W1,
                                         const float* __restrict__ b1,
                                         int c, int n, int hi) {
    unsigned w[4];
#pragma unroll
    for (int p = 0; p < 4; ++p) {
        const int k0 = 8 * hi + 2 * p;
        float a = (k0 < 17) ? W1[(size_t)k0 * 64 + 16 * c + n] * LOG2E
                            : (k0 == 17 ? b1[16 * c + n] * LOG2E : 0.0f);
        const int k1 = k0 + 1;
        float b = (k1 < 17) ? W1[(size_t)k1 * 64 + 16 * c + n] * LOG2E
                            : (k1 == 17 ? b1[16 * c + n] * LOG2E : 0.0f);
        w[p] = packh(a, b);
    }
    return mk8h(w[0], w[1], w[2], w[3]);
}

__device__ __forceinline__ f32x4 ldb4s(const float* p, float s) {
    f32x4 v = *(const f32x4*)p;
    v.x *= s; v.y *= s; v.z *= s; v.w *= s;
    return v;
}

__global__ __launch_bounds__(256, 2) void noprop_mfma_kernel(
    const float* __restrict__ eta,
    const float* __restrict__ W1, const float* __restrict__ b1,
    const float* __restrict__ W2, const float* __restrict__ b2,
    const float* __restrict__ W3, const float* __restrict__ b3,
    const float* __restrict__ W4, const float* __restrict__ b4,
    float* __restrict__ out, int batch)
{
    const int lane = threadIdx.x & 63;
    const int n  = lane & 15;
    const int hi = lane >> 4;

    // ---- weight fragments in LDS: [frag 0..16][lane 0..63], 16B each.
    __shared__ half8 wlds[17 * 64];
    if (threadIdx.x < 64) {
#pragma unroll
        for (int c = 0; c < 4; ++c)
            wlds[c * 64 + lane] = w1fragh(W1, b1, c, n, hi);
#pragma unroll
        for (int c = 0; c < 4; ++c)
#pragma unroll
            for (int s = 0; s < 2; ++s)
                wlds[(4 + 2 * c + s) * 64 + lane] = wfragh<64, 64, false, true>(W2, 1.0f, c, s, n, hi);
#pragma unroll
        for (int c = 0; c < 2; ++c)
#pragma unroll
            for (int s = 0; s < 2; ++s)
                wlds[(12 + 2 * c + s) * 64 + lane] = wfragh<32, 64, false, true>(W3, 1.0f, c, s, n, hi);
        wlds[16 * 64 + lane] = wfragh<8, 32, true, true>(W4, LN2, 0, 0, n, hi);
    }

    f32x4 zero4 = {0.f, 0.f, 0.f, 0.f};
    f32x4 B2b[4], B3b[2], B4b;
#pragma unroll
    for (int c = 0; c < 4; ++c) B2b[c] = ldb4s(b2 + 16 * c + 4 * hi, LOG2E);
#pragma unroll
    for (int c = 0; c < 2; ++c) B3b[c] = ldb4s(b3 + 16 * c + 4 * hi, LOG2E);
    B4b = (hi < 2) ? *(const f32x4*)(b4 + 4 * hi) : zero4;

    __syncthreads();   // once; weights are read-only afterwards

    // precomputed LDS base; frag f at literal offset f*1024
    const char* wbase = reinterpret_cast<const char*>(wlds) + (size_t)lane * 16;
#define WFRAG(f) (*reinterpret_cast<const half8*>(wbase + (f) * 1024))

    const bool is0 = (hi == 0);
    const bool is2 = (hi == 2);

    const int nTiles = batch >> 4;
    const int gwave  = (int)((blockIdx.x * blockDim.x + threadIdx.x) >> 6);
    const int nWaves = (int)((gridDim.x * blockDim.x) >> 6);

    for (int tile = gwave; tile < nTiles; tile += nWaves) {
        const int row = (tile << 4) + n;
        const float* erow = eta + (size_t)row * 8;

        f32x4 e0 = *(const f32x4*)(erow);
        f32x4 e1 = *(const f32x4*)(erow + 4);

        f32x4 stD = zero4;
        if (hi == 0) stD = e0;
        if (hi == 1) stD = e1;

        const unsigned base0 = (hi == 1) ? pkrtz(e0.x, e0.y) : 0u;
        const unsigned base1 = (hi == 1) ? pkrtz(e0.z, e0.w) : 0u;
        const unsigned base2 = (hi == 1) ? pkrtz(e1.x, e1.y) : 0u;
        const unsigned base3 = (hi == 1) ? pkrtz(e1.z, e1.w) : 0u;

#pragma unroll
        for (int step = 0; step < NSTEP; ++step) {
            const float t = DT * (float)step;         // literal after unroll
            const unsigned tw = pkrtz(t, 1.0f);       // literal after unroll

            const unsigned pa = pkrtz(stD.x, stD.y);
            const unsigned pb = pkrtz(stD.z, stD.w);
            const unsigned paP = partner16(pa);
            const unsigned pbP = partner16(pb);
            const unsigned b0  = is0 ? pa  : (is2 ? tw : base0);
            const unsigned b1w = is0 ? pb  : base1;
            const unsigned b2w = is0 ? paP : base2;
            const unsigned b3w = is0 ? pbP : base3;
            half8 Bx = mk8h(b0, b1w, b2w, b3w);

            // ---- layer 1 (17(+t,+1) -> 64), natural k-order
            f32x4 a1[4];
#pragma unroll
            for (int c = 0; c < 4; ++c)
                a1[c] = mfma16(WFRAG(c), Bx, zero4);
            unsigned w1w[8];
#pragma unroll
            for (int c = 0; c < 4; ++c) {
                w1w[2 * c]     = swish2(a1[c].x, a1[c].y);
                w1w[2 * c + 1] = swish2(a1[c].z, a1[c].w);
            }
            half8 h1f0 = mk8h(w1w[0], w1w[1], w1w[2], w1w[3]);
            half8 h1f1 = mk8h(w1w[4], w1w[5], w1w[6], w1w[7]);

            // ---- layer 2 (64 -> 64)
            f32x4 a2[4];
#pragma unroll
            for (int c = 0; c < 4; ++c) {
                f32x4 t0 = mfma16(WFRAG(4 + 2 * c), h1f0, B2b[c]);
                a2[c]    = mfma16(WFRAG(5 + 2 * c), h1f1, t0);
            }
            unsigned w2w[8];
#pragma unroll
            for (int c = 0; c < 4; ++c) {
                w2w[2 * c]     = swish2(a2[c].x, a2[c].y);
                w2w[2 * c + 1] = swish2(a2[c].z, a2[c].w);
            }
            half8 h2f0 = mk8h(w2w[0], w2w[1], w2w[2], w2w[3]);
            half8 h2f1 = mk8h(w2w[4], w2w[5], w2w[6], w2w[7]);

            // ---- layer 3 (64 -> 32)
            f32x4 a3[2];
#pragma unroll
            for (int c = 0; c < 2; ++c) {
                f32x4 t0 = mfma16(WFRAG(12 + 2 * c), h2f0, B3b[c]);
                a3[c]    = mfma16(WFRAG(13 + 2 * c), h2f1, t0);
            }
            unsigned w3w[4];
#pragma unroll
            for (int c = 0; c < 2; ++c) {
                w3w[2 * c]     = swish2(a3[c].x, a3[c].y);
                w3w[2 * c + 1] = swish2(a3[c].z, a3[c].w);
            }
            half8 h3f = mk8h(w3w[0], w3w[1], w3w[2], w3w[3]);

            // ---- layer 4 (32 -> 8, true domain) + Euler update (fp32)
            f32x4 a4 = mfma16(WFRAG(16), h3f, B4b);
            stD.x = fmaf(DT, a4.x, stD.x);
            stD.y = fmaf(DT, a4.y, stD.y);
            stD.z = fmaf(DT, a4.z, stD.z);
            stD.w = fmaf(DT, a4.w, stD.w);
        }

        if (hi < 2) *(f32x4*)(out + (size_t)row * 8 + 4 * hi) = stD;
    }
#undef WFRAG
}

extern "C" void kernel_launch(void* const* d_in, const int* in_sizes, int n_in,
                              void* d_out, int out_size, void* d_ws, size_t ws_size,
                              hipStream_t stream) {
    const float* eta = (const float*)d_in[0];
    const float* W1  = (const float*)d_in[1];
    const float* b1  = (const float*)d_in[2];
    const float* W2  = (const float*)d_in[3];
    const float* b2  = (const float*)d_in[4];
    const float* W3  = (const float*)d_in[5];
    const float* b3  = (const float*)d_in[6];
    const float* W4  = (const float*)d_in[7];
    const float* b4  = (const float*)d_in[8];
    float* out = (float*)d_out;

    const int batch = in_sizes[0] / 8;
    const int block = 256;   // 4 waves
    const int grid  = 2048;  // 8192 waves -> 16 tiles/wave
    hipLaunchKernelGGL(noprop_mfma_kernel, dim3(grid), dim3(block), 0, stream,
                       eta, W1, b1, W2, b2, W3, b3, W4, b4, out, batch);
}

// Round 20
// 655.408 us; speedup vs baseline: 1.1421x; 1.1421x over previous
//
#include <hip/hip_runtime.h>
#include <hip/hip_fp16.h>

// NoPropCTMomentNet: 10-step Euler of a 17->64->64->32->8 swish MLP, B=2M rows.
// Round 20 = exact revert to R17 (best: 656 us, absmax 0.03125).
// R19 falsified the AGPR-marshal theory (VGPR stayed 52 under "v" pins; nops
// only added stalls). R17 is the measured optimum of this design family:
// fp16 MFMA, weights in LDS (ds_read offset:N), algebraic k-permutation
// (no transposes), zero-trans bit-trick swish, fully unrolled step loop.
// Kernel is VALU-issue-bound: ~640 instr/tile-step measured vs ~320 written.

typedef __attribute__((ext_vector_type(8))) _Float16 half8;
typedef __attribute__((ext_vector_type(4))) float f32x4;

constexpr int NSTEP = 10;
constexpr float DT = 0.1f;
constexpr float LOG2E = 1.44269504f;
constexpr float LN2   = 0.69314718f;

__device__ __forceinline__ unsigned packh(float a, float b) {
    __half2 h = __floats2half2_rn(a, b);
    unsigned r; __builtin_memcpy(&r, &h, 4); return r;
}
__device__ __forceinline__ unsigned pkrtz(float a, float b) {
    auto z = __builtin_amdgcn_cvt_pkrtz(a, b);
    unsigned r; __builtin_memcpy(&r, &z, 4); return r;
}
__device__ __forceinline__ half8 mk8h(unsigned w0, unsigned w1,
                                      unsigned w2, unsigned w3) {
    union { unsigned w[4]; half8 h; } u;
    u.w[0] = w0; u.w[1] = w1; u.w[2] = w2; u.w[3] = w3;
    return u.h;
}

__device__ __forceinline__ void plswap16(unsigned& a, unsigned& b) {
    auto r = __builtin_amdgcn_permlane16_swap(a, b, false, false);
    a = r[0]; b = r[1];
}
__device__ __forceinline__ unsigned partner16(unsigned x) {
    unsigned a = x, b = x;
    plswap16(a, b);
    return b;
}

__device__ __forceinline__ __half2 bith2(unsigned u) {
    __half2 h; __builtin_memcpy(&h, &u, 4); return h;
}
__device__ __forceinline__ unsigned h2bit(__half2 h) {
    unsigned u; __builtin_memcpy(&u, &h, 4); return u;
}

// swish in scaled domain, 2 activations -> packed half2 word. Zero trans ops.
// g = max(z,0) + |z|*e*r(e);  e = 2^-|z| via f16 bit-trick
// bits = sat_u32(15324 - 1024|z|);  r(e) = -1/(1+e) deg-2 poly.
__device__ __forceinline__ unsigned swish2(float za, float zb) {
    const float ta = fmaf(__builtin_fabsf(za), -1024.0f, 15324.0f);
    const float tb = fmaf(__builtin_fabsf(zb), -1024.0f, 15324.0f);
    unsigned ua, ub;
    asm("v_cvt_u32_f32 %0, %1" : "=v"(ua) : "v"(ta));   // saturates: neg -> 0
    asm("v_cvt_u32_f32 %0, %1" : "=v"(ub) : "v"(tb));
    const unsigned eu = ua | (ub << 16);                // packed f16 pair e
    const unsigned zu = pkrtz(za, zb);
    __half2 z = bith2(zu), e = bith2(eu);
    __half2 az = __habs2(z);
    unsigned relu_u, zero_u = 0;
    asm("v_pk_max_f16 %0, %1, %2" : "=v"(relu_u) : "v"(zu), "v"(zero_u));
    const __half2 C0 = __float2half2_rn(-0.9903978f);
    const __half2 C1 = __float2half2_rn( 0.8141289f);
    const __half2 C2 = __float2half2_rn(-0.3292181f);
    __half2 s = __hmul2(az, e);
    __half2 r = __hfma2(e, __hfma2(e, C2, C1), C0);
    __half2 hh = __hfma2(s, r, bith2(relu_u));
    return h2bit(hh);
}

// A-fragment of W^T (chunk c, k-split s), fp16, scaled.
// PERM=true: k = 16(2s + (p>>1)) + 4hi + 2(p&1)  — matches prev-layer D layout.
template <int NOUT, int KLIM, bool M8, bool PERM>
__device__ __forceinline__ half8 wfragh(const float* __restrict__ W, float scale,
                                        int c, int s, int n, int hi) {
    unsigned w[4];
#pragma unroll
    for (int p = 0; p < 4; ++p) {
        const int k0 = PERM ? (16 * (2 * s + (p >> 1)) + 4 * hi + 2 * (p & 1))
                            : (32 * s + 8 * hi + 2 * p);
        const bool mok = !M8 || (n < 8);
        float a = (mok && (k0     < KLIM)) ? W[(size_t)k0 * NOUT + 16 * c + n] * scale : 0.0f;
        float b = (mok && (k0 + 1 < KLIM)) ? W[(size_t)(k0 + 1) * NOUT + 16 * c + n] * scale : 0.0f;
        w[p] = packh(a, b);
    }
    return mk8h(w[0], w[1], w[2], w[3]);
}

// W1 fragment with t-coeff at k=16 and bias at k=17 (virtual rows), scaled.
__device__ __forceinline__ half8 w1fragh(const float* __restrict__ W1,
                                         const float* __restrict__ b1,
                                         int c, int n, int hi) {
    unsigned w[4];
#pragma unroll
    for (int p = 0; p < 4; ++p) {
        const int k0 = 8 * hi + 2 * p;
        float a = (k0 < 17) ? W1[(size_t)k0 * 64 + 16 * c + n] * LOG2E
                            : (k0 == 17 ? b1[16 * c + n] * LOG2E : 0.0f);
        const int k1 = k0 + 1;
        float b = (k1 < 17) ? W1[(size_t)k1 * 64 + 16 * c + n] * LOG2E
                            : (k1 == 17 ? b1[16 * c + n] * LOG2E : 0.0f);
        w[p] = packh(a, b);
    }
    return mk8h(w[0], w[1], w[2], w[3]);
}

__device__ __forceinline__ f32x4 ldb4s(const float* p, float s) {
    f32x4 v = *(const f32x4*)p;
    v.x *= s; v.y *= s; v.z *= s; v.w *= s;
    return v;
}

__global__ __launch_bounds__(256, 2) void noprop_mfma_kernel(
    const float* __restrict__ eta,
    const float* __restrict__ W1, const float* __restrict__ b1,
    const float* __restrict__ W2, const float* __restrict__ b2,
    const float* __restrict__ W3, const float* __restrict__ b3,
    const float* __restrict__ W4, const float* __restrict__ b4,
    float* __restrict__ out, int batch)
{
    const int lane = threadIdx.x & 63;
    const int n  = lane & 15;
    const int hi = lane >> 4;

    // ---- weight fragments in LDS: [frag 0..16][lane 0..63], 16B each.
    __shared__ half8 wlds[17 * 64];
    if (threadIdx.x < 64) {
#pragma unroll
        for (int c = 0; c < 4; ++c)
            wlds[c * 64 + lane] = w1fragh(W1, b1, c, n, hi);
#pragma unroll
        for (int c = 0; c < 4; ++c)
#pragma unroll
            for (int s = 0; s < 2; ++s)
                wlds[(4 + 2 * c + s) * 64 + lane] = wfragh<64, 64, false, true>(W2, 1.0f, c, s, n, hi);
#pragma unroll
        for (int c = 0; c < 2; ++c)
#pragma unroll
            for (int s = 0; s < 2; ++s)
                wlds[(12 + 2 * c + s) * 64 + lane] = wfragh<32, 64, false, true>(W3, 1.0f, c, s, n, hi);
        wlds[16 * 64 + lane] = wfragh<8, 32, true, true>(W4, LN2, 0, 0, n, hi);
    }

    f32x4 zero4 = {0.f, 0.f, 0.f, 0.f};
    f32x4 B2b[4], B3b[2], B4b;
#pragma unroll
    for (int c = 0; c < 4; ++c) B2b[c] = ldb4s(b2 + 16 * c + 4 * hi, LOG2E);
#pragma unroll
    for (int c = 0; c < 2; ++c) B3b[c] = ldb4s(b3 + 16 * c + 4 * hi, LOG2E);
    B4b = (hi < 2) ? *(const f32x4*)(b4 + 4 * hi) : zero4;

    __syncthreads();   // once; weights are read-only afterwards

    // precomputed LDS base; frag f at literal offset f*1024
    const char* wbase = reinterpret_cast<const char*>(wlds) + (size_t)lane * 16;
#define WFRAG(f) (*reinterpret_cast<const half8*>(wbase + (f) * 1024))

    const bool is0 = (hi == 0);
    const bool is2 = (hi == 2);

    const int nTiles = batch >> 4;
    const int gwave  = (int)((blockIdx.x * blockDim.x + threadIdx.x) >> 6);
    const int nWaves = (int)((gridDim.x * blockDim.x) >> 6);

    for (int tile = gwave; tile < nTiles; tile += nWaves) {
        const int row = (tile << 4) + n;
        const float* erow = eta + (size_t)row * 8;

        f32x4 e0 = *(const f32x4*)(erow);
        f32x4 e1 = *(const f32x4*)(erow + 4);

        f32x4 stD = zero4;
        if (hi == 0) stD = e0;
        if (hi == 1) stD = e1;

        const unsigned base0 = (hi == 1) ? pkrtz(e0.x, e0.y) : 0u;
        const unsigned base1 = (hi == 1) ? pkrtz(e0.z, e0.w) : 0u;
        const unsigned base2 = (hi == 1) ? pkrtz(e1.x, e1.y) : 0u;
        const unsigned base3 = (hi == 1) ? pkrtz(e1.z, e1.w) : 0u;

#pragma unroll
        for (int step = 0; step < NSTEP; ++step) {
            const float t = DT * (float)step;         // literal after unroll
            const unsigned tw = pkrtz(t, 1.0f);       // literal after unroll

            const unsigned pa = pkrtz(stD.x, stD.y);
            const unsigned pb = pkrtz(stD.z, stD.w);
            const unsigned paP = partner16(pa);
            const unsigned pbP = partner16(pb);
            const unsigned b0  = is0 ? pa  : (is2 ? tw : base0);
            const unsigned b1w = is0 ? pb  : base1;
            const unsigned b2w = is0 ? paP : base2;
            const unsigned b3w = is0 ? pbP : base3;
            half8 Bx = mk8h(b0, b1w, b2w, b3w);

            // ---- layer 1 (17(+t,+1) -> 64), natural k-order
            f32x4 a1[4];
#pragma unroll
            for (int c = 0; c < 4; ++c)
                a1[c] = __builtin_amdgcn_mfma_f32_16x16x32_f16(WFRAG(c), Bx, zero4, 0, 0, 0);
            unsigned w1w[8];
#pragma unroll
            for (int c = 0; c < 4; ++c) {
                w1w[2 * c]     = swish2(a1[c].x, a1[c].y);
                w1w[2 * c + 1] = swish2(a1[c].z, a1[c].w);
            }
            half8 h1f0 = mk8h(w1w[0], w1w[1], w1w[2], w1w[3]);
            half8 h1f1 = mk8h(w1w[4], w1w[5], w1w[6], w1w[7]);

            // ---- layer 2 (64 -> 64)
            f32x4 a2[4];
#pragma unroll
            for (int c = 0; c < 4; ++c) {
                f32x4 t0 = __builtin_amdgcn_mfma_f32_16x16x32_f16(WFRAG(4 + 2 * c), h1f0, B2b[c], 0, 0, 0);
                a2[c]    = __builtin_amdgcn_mfma_f32_16x16x32_f16(WFRAG(5 + 2 * c), h1f1, t0, 0, 0, 0);
            }
            unsigned w2w[8];
#pragma unroll
            for (int c = 0; c < 4; ++c) {
                w2w[2 * c]     = swish2(a2[c].x, a2[c].y);
                w2w[2 * c + 1] = swish2(a2[c].z, a2[c].w);
            }
            half8 h2f0 = mk8h(w2w[0], w2w[1], w2w[2], w2w[3]);
            half8 h2f1 = mk8h(w2w[4], w2w[5], w2w[6], w2w[7]);

            // ---- layer 3 (64 -> 32)
            f32x4 a3[2];
#pragma unroll
            for (int c = 0; c < 2; ++c) {
                f32x4 t0 = __builtin_amdgcn_mfma_f32_16x16x32_f16(WFRAG(12 + 2 * c), h2f0, B3b[c], 0, 0, 0);
                a3[c]    = __builtin_amdgcn_mfma_f32_16x16x32_f16(WFRAG(13 + 2 * c), h2f1, t0, 0, 0, 0);
            }
            unsigned w3w[4];
#pragma unroll
            for (int c = 0; c < 2; ++c) {
                w3w[2 * c]     = swish2(a3[c].x, a3[c].y);
                w3w[2 * c + 1] = swish2(a3[c].z, a3[c].w);
            }
            half8 h3f = mk8h(w3w[0], w3w[1], w3w[2], w3w[3]);

            // ---- layer 4 (32 -> 8, true domain) + Euler update (fp32)
            f32x4 a4 = __builtin_amdgcn_mfma_f32_16x16x32_f16(WFRAG(16), h3f, B4b, 0, 0, 0);
            stD.x = fmaf(DT, a4.x, stD.x);
            stD.y = fmaf(DT, a4.y, stD.y);
            stD.z = fmaf(DT, a4.z, stD.z);
            stD.w = fmaf(DT, a4.w, stD.w);
        }

        if (hi < 2) *(f32x4*)(out + (size_t)row * 8 + 4 * hi) = stD;
    }
#undef WFRAG
}

extern "C" void kernel_launch(void* const* d_in, const int* in_sizes, int n_in,
                              void* d_out, int out_size, void* d_ws, size_t ws_size,
                              hipStream_t stream) {
    const float* eta = (const float*)d_in[0];
    const float* W1  = (const float*)d_in[1];
    const float* b1  = (const float*)d_in[2];
    const float* W2  = (const float*)d_in[3];
    const float* b2  = (const float*)d_in[4];
    const float* W3  = (const float*)d_in[5];
    const float* b3  = (const float*)d_in[6];
    const float* W4  = (const float*)d_in[7];
    const float* b4  = (const float*)d_in[8];
    float* out = (float*)d_out;

    const int batch = in_sizes[0] / 8;
    const int block = 256;   // 4 waves
    const int grid  = 2048;  // 8192 waves -> 16 tiles/wave
    hipLaunchKernelGGL(noprop_mfma_kernel, dim3(grid), dim3(block), 0, stream,
                       eta, W1, b1, W2, b2, W3, b3, W4, b4, out, batch);
}